// Round 1
// baseline (325.915 us; speedup 1.0000x reference)
//
#include <hip/hip_runtime.h>
#include <math.h>

#define NPROP 2000
#define NGT   100
#define HH    512
#define WW    512
#define TR    200
#define PMAX  66      // int(200*0.33)
#define MS    28

// ---------------- Kernel 1: selection, rois, class_ids, deltas ----------------
// grid = B(2) blocks, 512 threads.
__global__ __launch_bounds__(512) void k_select(
    const float* __restrict__ props,   // (B,2000,4)
    const int*   __restrict__ gcls,    // (B,100)
    const float* __restrict__ gbox,    // (B,100,4)
    float* __restrict__ out,
    int* __restrict__ wsi)
{
    const int b = blockIdx.x;
    const int t = threadIdx.x;
    const float* P  = props + (size_t)b * NPROP * 4;
    const float* GB = gbox  + (size_t)b * NGT * 4;
    const int*   GC = gcls  + (size_t)b * NGT;

    __shared__ float s_gb[NGT][4];
    __shared__ int   s_gc[NGT];
    __shared__ unsigned char s_fg[NGT], s_crowd[NGT];
    __shared__ float s_garea[NGT];
    __shared__ unsigned char s_pos[NPROP], s_neg[NPROP];
    __shared__ short s_assign[NPROP];
    __shared__ int s_selp[PMAX], s_seln[TR];
    __shared__ int s_wp[8], s_wn[8];
    __shared__ int s_totp, s_totn, s_np, s_nn;

    if (t < NGT) {
        float g0 = GB[t*4+0], g1 = GB[t*4+1], g2 = GB[t*4+2], g3 = GB[t*4+3];
        s_gb[t][0]=g0; s_gb[t][1]=g1; s_gb[t][2]=g2; s_gb[t][3]=g3;
        bool vg = (fabsf(g0)+fabsf(g1)+fabsf(g2)+fabsf(g3)) > 0.0f;
        int c = GC[t];
        s_gc[t] = c;
        s_fg[t]    = (unsigned char)(vg && (c > 0));
        s_crowd[t] = (unsigned char)(vg && (c < 0));
        s_garea[t] = __fmul_rn(__fsub_rn(g2,g0), __fsub_rn(g3,g1));
    }
    __syncthreads();

    // Phase A: per-proposal IoU row, flags, fg-argmax (first max index)
    for (int i = t; i < NPROP; i += 512) {
        float p0=P[i*4+0], p1=P[i*4+1], p2=P[i*4+2], p3=P[i*4+3];
        bool vp = (fabsf(p0)+fabsf(p1)+fabsf(p2)+fabsf(p3)) > 0.0f;
        float a1 = __fmul_rn(__fsub_rn(p2,p0), __fsub_rn(p3,p1));
        float crowd_max = 0.0f;
        float fgmax = 0.0f;
        float best = -INFINITY; int arg = 0;
        for (int g = 0; g < NGT; ++g) {
            float y1 = fmaxf(p0, s_gb[g][0]);
            float x1 = fmaxf(p1, s_gb[g][1]);
            float y2 = fminf(p2, s_gb[g][2]);
            float x2 = fminf(p3, s_gb[g][3]);
            float inter = __fmul_rn(fmaxf(__fsub_rn(x2,x1), 0.0f),
                                    fmaxf(__fsub_rn(y2,y1), 0.0f));
            float un = __fsub_rn(__fadd_rn(a1, s_garea[g]), inter);
            float iou = (un > 0.0f) ? __fdiv_rn(inter, un) : 0.0f;
            if (!vp) iou = 0.0f;
            if (s_crowd[g]) crowd_max = fmaxf(crowd_max, iou);
            float v;
            if (s_fg[g]) { fgmax = fmaxf(fgmax, iou); v = iou; }
            else         { v = -1.0f; }
            if (v > best) { best = v; arg = g; }   // strict > keeps FIRST max
        }
        s_pos[i]    = (unsigned char)((fgmax >= 0.5f) && vp);
        s_neg[i]    = (unsigned char)((fgmax < 0.5f) && (crowd_max < 0.001f) && vp);
        s_assign[i] = (short)arg;
    }
    __syncthreads();

    // Phase B/C: stable compaction via block prefix scan (4 elems/thread)
    int t4 = t * 4;
    int cp = 0, cn = 0;
    unsigned char lp[4], ln[4];
    #pragma unroll
    for (int e = 0; e < 4; ++e) {
        int i = t4 + e;
        unsigned char p = (i < NPROP) ? s_pos[i] : (unsigned char)0;
        unsigned char n = (i < NPROP) ? s_neg[i] : (unsigned char)0;
        lp[e] = p; ln[e] = n; cp += p; cn += n;
    }
    int ip = cp, inn = cn;
    int lane = t & 63;
    #pragma unroll
    for (int d = 1; d < 64; d <<= 1) {
        int vp2 = __shfl_up(ip, d);
        int vn2 = __shfl_up(inn, d);
        if (lane >= d) { ip += vp2; inn += vn2; }
    }
    if (lane == 63) { s_wp[t >> 6] = ip; s_wn[t >> 6] = inn; }
    __syncthreads();
    if (t == 0) {
        int ap = 0, an = 0;
        for (int w = 0; w < 8; ++w) {
            int tp = s_wp[w]; s_wp[w] = ap; ap += tp;
            int tn = s_wn[w]; s_wn[w] = an; an += tn;
        }
        s_totp = ap; s_totn = an;
    }
    __syncthreads();
    int ep = s_wp[t >> 6] + ip - cp;   // exclusive prefix (stable rank)
    int en = s_wn[t >> 6] + inn - cn;
    #pragma unroll
    for (int e = 0; e < 4; ++e) {
        if (lp[e]) { if (ep < PMAX) s_selp[ep] = t4 + e; ep++; }
        if (ln[e]) { if (en < TR)   s_seln[en] = t4 + e; en++; }
    }
    __syncthreads();

    if (t == 0) {
        int np = min(s_totp, PMAX);
        const float R = (float)(1.0 / 0.33);   // f32(3.0303030303...) as in JAX weak-typed mul
        int want = (int)floorf(__fmul_rn(R, (float)np)) - np;
        int nn = min(want, s_totn);
        nn = min(nn, TR - np);
        nn = max(nn, 0);
        s_np = np; s_nn = nn;
        wsi[b] = np;
    }
    __syncthreads();

    // Phase D: write rois / class_ids / deltas; stash positive rows for kernel 2
    if (t < TR) {
        const int j = t;
        const int np = s_np, nn = s_nn;
        const bool isp  = j < np;
        const bool kept = j < np + nn;
        float r0=0, r1=0, r2=0, r3=0, cid=0, d0=0, d1=0, d2=0, d3=0;
        if (kept) {
            int sel = isp ? s_selp[j] : s_seln[j - np];
            r0 = P[sel*4+0]; r1 = P[sel*4+1]; r2 = P[sel*4+2]; r3 = P[sel*4+3];
            if (isp) {
                int g = (int)s_assign[sel];
                cid = (float)s_gc[g];
                float h  = __fsub_rn(r2, r0), w = __fsub_rn(r3, r1);
                float cy = __fadd_rn(r0, __fmul_rn(0.5f, h));
                float cx = __fadd_rn(r1, __fmul_rn(0.5f, w));
                float gh  = __fsub_rn(s_gb[g][2], s_gb[g][0]);
                float gw  = __fsub_rn(s_gb[g][3], s_gb[g][1]);
                float gcy = __fadd_rn(s_gb[g][0], __fmul_rn(0.5f, gh));
                float gcx = __fadd_rn(s_gb[g][1], __fmul_rn(0.5f, gw));
                d0 = __fdiv_rn(__fdiv_rn(__fsub_rn(gcy, cy), h), 0.1f);
                d1 = __fdiv_rn(__fdiv_rn(__fsub_rn(gcx, cx), w), 0.1f);
                d2 = __fdiv_rn(logf(__fdiv_rn(gh, h)), 0.2f);
                d3 = __fdiv_rn(logf(__fdiv_rn(gw, w)), 0.2f);
                if (j < PMAX) {
                    wsi[2 + b*PMAX + j] = g;
                    float* wsf = (float*)(wsi + 2 + 2*PMAX);
                    wsf[(b*PMAX + j)*4 + 0] = r0;
                    wsf[(b*PMAX + j)*4 + 1] = r1;
                    wsf[(b*PMAX + j)*4 + 2] = r2;
                    wsf[(b*PMAX + j)*4 + 3] = r3;
                }
            }
        }
        // rois (2,200,4) @0 ; class_ids (2,200) @1600 ; deltas (2,200,4) @2000
        out[(size_t)b*TR*4 + j*4 + 0] = r0;
        out[(size_t)b*TR*4 + j*4 + 1] = r1;
        out[(size_t)b*TR*4 + j*4 + 2] = r2;
        out[(size_t)b*TR*4 + j*4 + 3] = r3;
        out[1600 + (size_t)b*TR + j] = cid;
        out[2000 + (size_t)b*TR*4 + j*4 + 0] = d0;
        out[2000 + (size_t)b*TR*4 + j*4 + 1] = d1;
        out[2000 + (size_t)b*TR*4 + j*4 + 2] = d2;
        out[2000 + (size_t)b*TR*4 + j*4 + 3] = d3;
    }
}

// ---------------- Kernel 2: masks (2,200,28,28) @3600 ----------------
// grid = B*TR blocks, 256 threads; one block per (b, roi-row)
__global__ __launch_bounds__(256) void k_masks(
    const int* __restrict__ gmask,   // (B,512,512,100) bool staged as int32
    const int* __restrict__ wsi,
    float* __restrict__ out)
{
    const int bid = blockIdx.x;
    const int b = bid / TR, j = bid % TR;
    float* mout = out + 3600 + (size_t)b*TR*MS*MS + (size_t)j*MS*MS;
    const int np = wsi[b];
    if (j >= np) {
        for (int p = threadIdx.x; p < MS*MS; p += 256) mout[p] = 0.0f;
        return;
    }
    const int g = wsi[2 + b*PMAX + j];
    const float* wsf = (const float*)(wsi + 2 + 2*PMAX);
    const float y1 = wsf[(b*PMAX + j)*4 + 0];
    const float x1 = wsf[(b*PMAX + j)*4 + 1];
    const float y2 = wsf[(b*PMAX + j)*4 + 2];
    const float x2 = wsf[(b*PMAX + j)*4 + 3];

    const float sy = __fdiv_rn(__fmul_rn(__fsub_rn(y2, y1), 511.0f), 27.0f);
    const float sx = __fdiv_rn(__fmul_rn(__fsub_rn(x2, x1), 511.0f), 27.0f);
    const float by = __fmul_rn(y1, 511.0f);
    const float bx = __fmul_rn(x1, 511.0f);
    const int* GM = gmask + (size_t)b * HH * WW * NGT + g;

    for (int p = threadIdx.x; p < MS*MS; p += 256) {
        int iy = p / MS, ix = p % MS;
        float ys = __fadd_rn(by, __fmul_rn((float)iy, sy));
        float xs = __fadd_rn(bx, __fmul_rn((float)ix, sx));
        float y0f = floorf(ys), x0f = floorf(xs);
        float wy = __fsub_rn(ys, y0f);
        float wx = __fsub_rn(xs, x0f);
        int y0i = (int)fminf(fmaxf(y0f, 0.0f), 511.0f);
        int y1i = (int)fminf(fmaxf(__fadd_rn(y0f, 1.0f), 0.0f), 511.0f);
        int x0i = (int)fminf(fmaxf(x0f, 0.0f), 511.0f);
        int x1i = (int)fminf(fmaxf(__fadd_rn(x0f, 1.0f), 0.0f), 511.0f);
        float v00 = (float)GM[((size_t)y0i * WW + x0i) * NGT];
        float v01 = (float)GM[((size_t)y0i * WW + x1i) * NGT];
        float v10 = (float)GM[((size_t)y1i * WW + x0i) * NGT];
        float v11 = (float)GM[((size_t)y1i * WW + x1i) * NGT];
        float omwx = __fsub_rn(1.0f, wx), omwy = __fsub_rn(1.0f, wy);
        float top = __fadd_rn(__fmul_rn(v00, omwx), __fmul_rn(v01, wx));
        float bot = __fadd_rn(__fmul_rn(v10, omwx), __fmul_rn(v11, wx));
        float val = __fadd_rn(__fmul_rn(top, omwy), __fmul_rn(bot, wy));
        bool ok = (ys >= 0.0f) && (ys <= 511.0f) && (xs >= 0.0f) && (xs <= 511.0f);
        val = ok ? val : 0.0f;
        mout[p] = rintf(val);   // jnp.round = half-to-even
    }
}

extern "C" void kernel_launch(void* const* d_in, const int* in_sizes, int n_in,
                              void* d_out, int out_size, void* d_ws, size_t ws_size,
                              hipStream_t stream) {
    const float* props = (const float*)d_in[0];   // (2,2000,4) f32
    const int*   gcls  = (const int*)  d_in[1];   // (2,100) i32
    const float* gbox  = (const float*)d_in[2];   // (2,100,4) f32
    const int*   gmask = (const int*)  d_in[3];   // (2,512,512,100) bool->i32
    float* out = (float*)d_out;
    int* wsi = (int*)d_ws;

    k_select<<<2, 512, 0, stream>>>(props, gcls, gbox, out, wsi);
    k_masks<<<2 * TR, 256, 0, stream>>>(gmask, wsi, out);
}

// Round 2
// 276.547 us; speedup vs baseline: 1.1785x; 1.1785x over previous
//
#include <hip/hip_runtime.h>
#include <math.h>

#define NPROP 2000
#define NGT   100
#define HH    512
#define WW    512
#define TR    200
#define PMAX  66      // int(200*0.33)
#define MS    28
#define FLAGS_OFF 4096   // int offset into d_ws for per-proposal flag words

// ---------------- Kernel A: per-proposal IoU flags (parallel over 4000 proposals) ----
// grid = (8, B), block = 256. flag word: bit0=pos, bit1=neg, bits2..8=assign gt idx.
__global__ __launch_bounds__(256) void k_flags(
    const float* __restrict__ props,   // (B,2000,4)
    const int*   __restrict__ gcls,    // (B,100)
    const float* __restrict__ gbox,    // (B,100,4)
    int* __restrict__ wsi)
{
    const int b = blockIdx.y;
    const int i = blockIdx.x * 256 + threadIdx.x;
    const float* P  = props + (size_t)b * NPROP * 4;
    const float* GB = gbox  + (size_t)b * NGT * 4;
    const int*   GC = gcls  + (size_t)b * NGT;

    __shared__ float s_gb[NGT][4];
    __shared__ float s_garea[NGT];
    __shared__ unsigned char s_fg[NGT], s_crowd[NGT];

    if (threadIdx.x < NGT) {
        int t = threadIdx.x;
        float g0 = GB[t*4+0], g1 = GB[t*4+1], g2 = GB[t*4+2], g3 = GB[t*4+3];
        s_gb[t][0]=g0; s_gb[t][1]=g1; s_gb[t][2]=g2; s_gb[t][3]=g3;
        bool vg = (fabsf(g0)+fabsf(g1)+fabsf(g2)+fabsf(g3)) > 0.0f;
        int c = GC[t];
        s_fg[t]    = (unsigned char)(vg && (c > 0));
        s_crowd[t] = (unsigned char)(vg && (c < 0));
        s_garea[t] = __fmul_rn(__fsub_rn(g2,g0), __fsub_rn(g3,g1));
    }
    __syncthreads();

    if (i >= NPROP) return;
    float p0=P[i*4+0], p1=P[i*4+1], p2=P[i*4+2], p3=P[i*4+3];
    bool vp = (fabsf(p0)+fabsf(p1)+fabsf(p2)+fabsf(p3)) > 0.0f;
    float a1 = __fmul_rn(__fsub_rn(p2,p0), __fsub_rn(p3,p1));
    float crowd_max = 0.0f, fgmax = 0.0f;
    float best = -INFINITY; int arg = 0;
    for (int g = 0; g < NGT; ++g) {
        float y1 = fmaxf(p0, s_gb[g][0]);
        float x1 = fmaxf(p1, s_gb[g][1]);
        float y2 = fminf(p2, s_gb[g][2]);
        float x2 = fminf(p3, s_gb[g][3]);
        float inter = __fmul_rn(fmaxf(__fsub_rn(x2,x1), 0.0f),
                                fmaxf(__fsub_rn(y2,y1), 0.0f));
        float un = __fsub_rn(__fadd_rn(a1, s_garea[g]), inter);
        float iou = (un > 0.0f) ? __fdiv_rn(inter, un) : 0.0f;
        if (!vp) iou = 0.0f;
        if (s_crowd[g]) crowd_max = fmaxf(crowd_max, iou);
        float v;
        if (s_fg[g]) { fgmax = fmaxf(fgmax, iou); v = iou; }
        else         { v = -1.0f; }
        if (v > best) { best = v; arg = g; }   // strict > keeps FIRST max index
    }
    int pos = (int)((fgmax >= 0.5f) && vp);
    int neg = (int)((fgmax < 0.5f) && (crowd_max < 0.001f) && vp);
    wsi[FLAGS_OFF + b*NPROP + i] = pos | (neg << 1) | (arg << 2);
}

// ---------------- Kernel B: stable compaction + rois/class_ids/deltas -----------
// grid = B blocks, 512 threads.
__global__ __launch_bounds__(512) void k_pick(
    const float* __restrict__ props,
    const int*   __restrict__ gcls,
    const float* __restrict__ gbox,
    float* __restrict__ out,
    int* __restrict__ wsi)
{
    const int b = blockIdx.x;
    const int t = threadIdx.x;
    const float* P  = props + (size_t)b * NPROP * 4;
    const float* GB = gbox  + (size_t)b * NGT * 4;
    const int*   GC = gcls  + (size_t)b * NGT;
    const int*   F  = wsi + FLAGS_OFF + b * NPROP;

    __shared__ int s_selp[PMAX], s_seln[TR], s_selpg[PMAX];
    __shared__ int s_wp[8], s_wn[8];
    __shared__ int s_totp, s_totn, s_np, s_nn;

    // stable block-wide compaction, 4 proposals per thread
    int t4 = t * 4;
    int fl[4]; int cp = 0, cn = 0;
    #pragma unroll
    for (int e = 0; e < 4; ++e) {
        int i = t4 + e;
        fl[e] = (i < NPROP) ? F[i] : 0;
        cp += (fl[e] & 1); cn += ((fl[e] >> 1) & 1);
    }
    int ip = cp, inn = cn;
    int lane = t & 63;
    #pragma unroll
    for (int d = 1; d < 64; d <<= 1) {
        int vp2 = __shfl_up(ip, d);
        int vn2 = __shfl_up(inn, d);
        if (lane >= d) { ip += vp2; inn += vn2; }
    }
    if (lane == 63) { s_wp[t >> 6] = ip; s_wn[t >> 6] = inn; }
    __syncthreads();
    if (t == 0) {
        int ap = 0, an = 0;
        for (int w = 0; w < 8; ++w) {
            int tp = s_wp[w]; s_wp[w] = ap; ap += tp;
            int tn = s_wn[w]; s_wn[w] = an; an += tn;
        }
        s_totp = ap; s_totn = an;
    }
    __syncthreads();
    int ep = s_wp[t >> 6] + ip - cp;   // exclusive stable rank
    int en = s_wn[t >> 6] + inn - cn;
    #pragma unroll
    for (int e = 0; e < 4; ++e) {
        if (fl[e] & 1) { if (ep < PMAX) { s_selp[ep] = t4 + e; s_selpg[ep] = (fl[e] >> 2) & 127; } ep++; }
        if ((fl[e] >> 1) & 1) { if (en < TR) s_seln[en] = t4 + e; en++; }
    }
    __syncthreads();

    if (t == 0) {
        int np = min(s_totp, PMAX);
        const float R = (float)(1.0 / 0.33);
        int want = (int)floorf(__fmul_rn(R, (float)np)) - np;
        int nn = min(want, s_totn);
        nn = min(nn, TR - np);
        nn = max(nn, 0);
        s_np = np; s_nn = nn;
        wsi[b] = np;
    }
    __syncthreads();

    if (t < TR) {
        const int j = t;
        const int np = s_np, nn = s_nn;
        const bool isp  = j < np;
        const bool kept = j < np + nn;
        float r0=0, r1=0, r2=0, r3=0, cid=0, d0=0, d1=0, d2=0, d3=0;
        if (kept) {
            int sel = isp ? s_selp[j] : s_seln[j - np];
            r0 = P[sel*4+0]; r1 = P[sel*4+1]; r2 = P[sel*4+2]; r3 = P[sel*4+3];
            if (isp) {
                int g = s_selpg[j];
                cid = (float)GC[g];
                float gb0 = GB[g*4+0], gb1 = GB[g*4+1], gb2 = GB[g*4+2], gb3 = GB[g*4+3];
                float h  = __fsub_rn(r2, r0), w = __fsub_rn(r3, r1);
                float cy = __fadd_rn(r0, __fmul_rn(0.5f, h));
                float cx = __fadd_rn(r1, __fmul_rn(0.5f, w));
                float gh  = __fsub_rn(gb2, gb0);
                float gw  = __fsub_rn(gb3, gb1);
                float gcy = __fadd_rn(gb0, __fmul_rn(0.5f, gh));
                float gcx = __fadd_rn(gb1, __fmul_rn(0.5f, gw));
                d0 = __fdiv_rn(__fdiv_rn(__fsub_rn(gcy, cy), h), 0.1f);
                d1 = __fdiv_rn(__fdiv_rn(__fsub_rn(gcx, cx), w), 0.1f);
                d2 = __fdiv_rn(logf(__fdiv_rn(gh, h)), 0.2f);
                d3 = __fdiv_rn(logf(__fdiv_rn(gw, w)), 0.2f);
                if (j < PMAX) {
                    wsi[2 + b*PMAX + j] = g;
                    float* wsf = (float*)(wsi + 2 + 2*PMAX);
                    wsf[(b*PMAX + j)*4 + 0] = r0;
                    wsf[(b*PMAX + j)*4 + 1] = r1;
                    wsf[(b*PMAX + j)*4 + 2] = r2;
                    wsf[(b*PMAX + j)*4 + 3] = r3;
                }
            }
        }
        out[(size_t)b*TR*4 + j*4 + 0] = r0;
        out[(size_t)b*TR*4 + j*4 + 1] = r1;
        out[(size_t)b*TR*4 + j*4 + 2] = r2;
        out[(size_t)b*TR*4 + j*4 + 3] = r3;
        out[1600 + (size_t)b*TR + j] = cid;
        out[2000 + (size_t)b*TR*4 + j*4 + 0] = d0;
        out[2000 + (size_t)b*TR*4 + j*4 + 1] = d1;
        out[2000 + (size_t)b*TR*4 + j*4 + 2] = d2;
        out[2000 + (size_t)b*TR*4 + j*4 + 3] = d3;
    }
}

// ---------------- Kernel C: masks (2,200,28,28) @3600 ----------------
__global__ __launch_bounds__(256) void k_masks(
    const int* __restrict__ gmask,   // (B,512,512,100) bool staged as int32
    const int* __restrict__ wsi,
    float* __restrict__ out)
{
    const int bid = blockIdx.x;
    const int b = bid / TR, j = bid % TR;
    float* mout = out + 3600 + (size_t)b*TR*MS*MS + (size_t)j*MS*MS;
    const int np = wsi[b];
    if (j >= np) {
        for (int p = threadIdx.x; p < MS*MS; p += 256) mout[p] = 0.0f;
        return;
    }
    const int g = wsi[2 + b*PMAX + j];
    const float* wsf = (const float*)(wsi + 2 + 2*PMAX);
    const float y1 = wsf[(b*PMAX + j)*4 + 0];
    const float x1 = wsf[(b*PMAX + j)*4 + 1];
    const float y2 = wsf[(b*PMAX + j)*4 + 2];
    const float x2 = wsf[(b*PMAX + j)*4 + 3];

    const float sy = __fdiv_rn(__fmul_rn(__fsub_rn(y2, y1), 511.0f), 27.0f);
    const float sx = __fdiv_rn(__fmul_rn(__fsub_rn(x2, x1), 511.0f), 27.0f);
    const float by = __fmul_rn(y1, 511.0f);
    const float bx = __fmul_rn(x1, 511.0f);
    const int* GM = gmask + (size_t)b * HH * WW * NGT + g;

    for (int p = threadIdx.x; p < MS*MS; p += 256) {
        int iy = p / MS, ix = p % MS;
        float ys = __fadd_rn(by, __fmul_rn((float)iy, sy));
        float xs = __fadd_rn(bx, __fmul_rn((float)ix, sx));
        float y0f = floorf(ys), x0f = floorf(xs);
        float wy = __fsub_rn(ys, y0f);
        float wx = __fsub_rn(xs, x0f);
        int y0i = (int)fminf(fmaxf(y0f, 0.0f), 511.0f);
        int y1i = (int)fminf(fmaxf(__fadd_rn(y0f, 1.0f), 0.0f), 511.0f);
        int x0i = (int)fminf(fmaxf(x0f, 0.0f), 511.0f);
        int x1i = (int)fminf(fmaxf(__fadd_rn(x0f, 1.0f), 0.0f), 511.0f);
        float v00 = (float)GM[((size_t)y0i * WW + x0i) * NGT];
        float v01 = (float)GM[((size_t)y0i * WW + x1i) * NGT];
        float v10 = (float)GM[((size_t)y1i * WW + x0i) * NGT];
        float v11 = (float)GM[((size_t)y1i * WW + x1i) * NGT];
        float omwx = __fsub_rn(1.0f, wx), omwy = __fsub_rn(1.0f, wy);
        float top = __fadd_rn(__fmul_rn(v00, omwx), __fmul_rn(v01, wx));
        float bot = __fadd_rn(__fmul_rn(v10, omwx), __fmul_rn(v11, wx));
        float val = __fadd_rn(__fmul_rn(top, omwy), __fmul_rn(bot, wy));
        bool ok = (ys >= 0.0f) && (ys <= 511.0f) && (xs >= 0.0f) && (xs <= 511.0f);
        val = ok ? val : 0.0f;
        mout[p] = rintf(val);   // jnp.round = half-to-even
    }
}

extern "C" void kernel_launch(void* const* d_in, const int* in_sizes, int n_in,
                              void* d_out, int out_size, void* d_ws, size_t ws_size,
                              hipStream_t stream) {
    const float* props = (const float*)d_in[0];   // (2,2000,4) f32
    const int*   gcls  = (const int*)  d_in[1];   // (2,100) i32
    const float* gbox  = (const float*)d_in[2];   // (2,100,4) f32
    const int*   gmask = (const int*)  d_in[3];   // (2,512,512,100) bool->i32
    float* out = (float*)d_out;
    int* wsi = (int*)d_ws;

    dim3 gA(8, 2);
    k_flags<<<gA, 256, 0, stream>>>(props, gcls, gbox, wsi);
    k_pick<<<2, 512, 0, stream>>>(props, gcls, gbox, out, wsi);
    k_masks<<<2 * TR, 256, 0, stream>>>(gmask, wsi, out);
}

// Round 3
// 270.962 us; speedup vs baseline: 1.2028x; 1.0206x over previous
//
#include <hip/hip_runtime.h>
#include <math.h>

#define NPROP 2000
#define NGT   100
#define HH    512
#define WW    512
#define TR    200
#define PMAX  66      // int(200*0.33)
#define MS    28
#define FLAGS_OFF 4096   // int offset in d_ws: per-proposal flag words (2 batches x 2000)
#define BITS_OFF  8192   // int offset in d_ws: per batch 64 pos words + 64 neg words

// ---------------- Kernel A: per-proposal IoU flags + selection bitmasks --------------
// grid = (16, B), block = 256; thread PAIR per proposal (each half does 50 GTs).
// flag word: bit0=pos, bit1=neg, bits2..8=assign gt idx.
__global__ __launch_bounds__(256) void k_flags(
    const float* __restrict__ props,   // (B,2000,4)
    const int*   __restrict__ gcls,    // (B,100)
    const float* __restrict__ gbox,    // (B,100,4)
    int* __restrict__ wsi)
{
    const int b = blockIdx.y;
    const int t = threadIdx.x;
    const int half = t & 1;
    const int pairLocal = t >> 1;                  // 0..127 within block
    const int pairId = blockIdx.x * 128 + pairLocal;
    const bool act = pairId < NPROP;
    const float* P  = props + (size_t)b * NPROP * 4;
    const float* GB = gbox  + (size_t)b * NGT * 4;
    const int*   GC = gcls  + (size_t)b * NGT;

    __shared__ float s_gb[NGT][4];
    __shared__ float s_garea[NGT];
    __shared__ unsigned char s_fg[NGT], s_crowd[NGT];
    __shared__ unsigned s_pw[4], s_nw[4];

    if (t < 4) { s_pw[t] = 0u; s_nw[t] = 0u; }
    if (t < NGT) {
        float g0 = GB[t*4+0], g1 = GB[t*4+1], g2 = GB[t*4+2], g3 = GB[t*4+3];
        s_gb[t][0]=g0; s_gb[t][1]=g1; s_gb[t][2]=g2; s_gb[t][3]=g3;
        bool vg = (fabsf(g0)+fabsf(g1)+fabsf(g2)+fabsf(g3)) > 0.0f;
        int c = GC[t];
        s_fg[t]    = (unsigned char)(vg && (c > 0));
        s_crowd[t] = (unsigned char)(vg && (c < 0));
        s_garea[t] = __fmul_rn(__fsub_rn(g2,g0), __fsub_rn(g3,g1));
    }
    __syncthreads();

    float p0=0.f, p1=0.f, p2=0.f, p3=0.f;
    if (act) { p0=P[pairId*4+0]; p1=P[pairId*4+1]; p2=P[pairId*4+2]; p3=P[pairId*4+3]; }
    bool vp = (fabsf(p0)+fabsf(p1)+fabsf(p2)+fabsf(p3)) > 0.0f;
    float a1 = __fmul_rn(__fsub_rn(p2,p0), __fsub_rn(p3,p1));
    float crowd_max = 0.0f, fgmax = 0.0f;
    float best = -INFINITY; int arg = half * 50;
    const int g0i = half * 50;
    for (int g = g0i; g < g0i + 50; ++g) {
        float y1 = fmaxf(p0, s_gb[g][0]);
        float x1 = fmaxf(p1, s_gb[g][1]);
        float y2 = fminf(p2, s_gb[g][2]);
        float x2 = fminf(p3, s_gb[g][3]);
        float inter = __fmul_rn(fmaxf(__fsub_rn(x2,x1), 0.0f),
                                fmaxf(__fsub_rn(y2,y1), 0.0f));
        float un = __fsub_rn(__fadd_rn(a1, s_garea[g]), inter);
        float iou = (un > 0.0f) ? __fdiv_rn(inter, un) : 0.0f;
        if (!vp) iou = 0.0f;
        if (s_crowd[g]) crowd_max = fmaxf(crowd_max, iou);
        float v;
        if (s_fg[g]) { fgmax = fmaxf(fgmax, iou); v = iou; }
        else         { v = -1.0f; }
        if (v > best) { best = v; arg = g; }   // strict > keeps FIRST max within half
    }
    // combine halves (pair = lanes 2k, 2k+1 of the same wave)
    float o;
    o = __shfl_xor(fgmax, 1);     fgmax = fmaxf(fgmax, o);
    o = __shfl_xor(crowd_max, 1); crowd_max = fmaxf(crowd_max, o);
    float ob = __shfl_xor(best, 1); int oa = __shfl_xor(arg, 1);
    float v_lo = half ? ob : best;  int a_lo = half ? oa : arg;
    float v_hi = half ? best : ob;  int a_hi = half ? arg : oa;
    int argf = (v_hi > v_lo) ? a_hi : a_lo;   // first-max: lo wins ties (lo indices smaller)
    int pos = (int)((fgmax >= 0.5f) && vp);
    int neg = (int)((fgmax < 0.5f) && (crowd_max < 0.001f) && vp);

    if (act && half == 0) {
        wsi[FLAGS_OFF + b*NPROP + pairId] = pos | (neg << 1) | (argf << 2);
        unsigned bit = 1u << (pairLocal & 31);
        int widx = pairLocal >> 5;             // wave index within block, 0..3
        if (pos) atomicOr(&s_pw[widx], bit);
        if (neg) atomicOr(&s_nw[widx], bit);
    }
    __syncthreads();
    if (t < 4) {
        unsigned* BW = (unsigned*)(wsi + BITS_OFF + b*128);
        int w = blockIdx.x * 4 + t;            // 0..63
        BW[w]      = s_pw[t];
        BW[64 + w] = s_nw[t];
    }
}

// ---------------- Kernel B: per-row pick + rois/class/deltas + masks -----------------
// grid = B*TR blocks, 256 threads; one block per (b, j) output row.
__global__ __launch_bounds__(256) void k_rows(
    const float* __restrict__ props,
    const int*   __restrict__ gcls,
    const float* __restrict__ gbox,
    const int*   __restrict__ gmask,   // (B,512,512,100) bool staged as int32
    const int*   __restrict__ wsi,
    float* __restrict__ out)
{
    const int bid = blockIdx.x;
    const int b = bid / TR, j = bid % TR;
    const int t = threadIdx.x;
    const int lane = t & 63, wave = t >> 6;
    const float* P  = props + (size_t)b * NPROP * 4;
    const float* GB = gbox  + (size_t)b * NGT * 4;
    const int*   GC = gcls  + (size_t)b * NGT;
    const unsigned* BW = (const unsigned*)(wsi + BITS_OFF + b*128);

    __shared__ unsigned s_w[2][63];
    __shared__ int s_tot[2];
    __shared__ int s_np, s_g;
    __shared__ float s_r[4];

    if (wave < 2) {                          // wave0: pos words, wave1: neg words
        unsigned w = (lane < 63) ? BW[wave*64 + lane] : 0u;
        if (lane < 63) s_w[wave][lane] = w;
        int c = __popc(w);
        #pragma unroll
        for (int d = 1; d < 64; d <<= 1) c += __shfl_xor(c, d);
        if (lane == 0) s_tot[wave] = c;
    }
    __syncthreads();

    if (t == 0) {
        int totp = s_tot[0], totn = s_tot[1];
        int np = min(totp, PMAX);
        const float R = (float)(1.0 / 0.33);
        int want = (int)floorf(__fmul_rn(R, (float)np)) - np;
        int nn = min(want, totn); nn = min(nn, TR - np); nn = max(nn, 0);
        s_np = np;
        const bool isp  = j < np;
        const bool kept = j < np + nn;
        float r0=0, r1=0, r2=0, r3=0, cid=0, d0=0, d1=0, d2=0, d3=0;
        int g = 0;
        if (kept) {
            int list = isp ? 0 : 1;
            int r = isp ? j : j - np;
            int sel = 0;
            for (int w = 0; w < 63; ++w) {
                unsigned word = s_w[list][w];
                int c = __popc(word);
                if (r < c) {
                    unsigned x = word;
                    for (int k = 0; k < r; ++k) x &= x - 1;  // clear r lowest set bits
                    sel = w*32 + (__ffs(x) - 1);
                    break;
                }
                r -= c;
            }
            r0 = P[sel*4+0]; r1 = P[sel*4+1]; r2 = P[sel*4+2]; r3 = P[sel*4+3];
            if (isp) {
                g = (wsi[FLAGS_OFF + b*NPROP + sel] >> 2) & 127;
                cid = (float)GC[g];
                float gb0 = GB[g*4+0], gb1 = GB[g*4+1], gb2 = GB[g*4+2], gb3 = GB[g*4+3];
                float h  = __fsub_rn(r2, r0), w = __fsub_rn(r3, r1);
                float cy = __fadd_rn(r0, __fmul_rn(0.5f, h));
                float cx = __fadd_rn(r1, __fmul_rn(0.5f, w));
                float gh  = __fsub_rn(gb2, gb0);
                float gw  = __fsub_rn(gb3, gb1);
                float gcy = __fadd_rn(gb0, __fmul_rn(0.5f, gh));
                float gcx = __fadd_rn(gb1, __fmul_rn(0.5f, gw));
                d0 = __fdiv_rn(__fdiv_rn(__fsub_rn(gcy, cy), h), 0.1f);
                d1 = __fdiv_rn(__fdiv_rn(__fsub_rn(gcx, cx), w), 0.1f);
                d2 = __fdiv_rn(logf(__fdiv_rn(gh, h)), 0.2f);
                d3 = __fdiv_rn(logf(__fdiv_rn(gw, w)), 0.2f);
            }
        }
        s_g = g; s_r[0]=r0; s_r[1]=r1; s_r[2]=r2; s_r[3]=r3;
        out[(size_t)b*TR*4 + j*4 + 0] = r0;
        out[(size_t)b*TR*4 + j*4 + 1] = r1;
        out[(size_t)b*TR*4 + j*4 + 2] = r2;
        out[(size_t)b*TR*4 + j*4 + 3] = r3;
        out[1600 + (size_t)b*TR + j] = cid;
        out[2000 + (size_t)b*TR*4 + j*4 + 0] = d0;
        out[2000 + (size_t)b*TR*4 + j*4 + 1] = d1;
        out[2000 + (size_t)b*TR*4 + j*4 + 2] = d2;
        out[2000 + (size_t)b*TR*4 + j*4 + 3] = d3;
    }
    __syncthreads();

    // masks row (2,200,28,28) @3600
    float* mout = out + 3600 + (size_t)b*TR*MS*MS + (size_t)j*MS*MS;
    if (j >= s_np) {
        for (int p = t; p < MS*MS; p += 256) mout[p] = 0.0f;
        return;
    }
    const float y1 = s_r[0], x1 = s_r[1], y2 = s_r[2], x2 = s_r[3];
    const float sy = __fdiv_rn(__fmul_rn(__fsub_rn(y2, y1), 511.0f), 27.0f);
    const float sx = __fdiv_rn(__fmul_rn(__fsub_rn(x2, x1), 511.0f), 27.0f);
    const float by = __fmul_rn(y1, 511.0f);
    const float bx = __fmul_rn(x1, 511.0f);
    const int* GM = gmask + (size_t)b * HH * WW * NGT + s_g;

    for (int p = t; p < MS*MS; p += 256) {
        int iy = p / MS, ix = p % MS;
        float ys = __fadd_rn(by, __fmul_rn((float)iy, sy));
        float xs = __fadd_rn(bx, __fmul_rn((float)ix, sx));
        float y0f = floorf(ys), x0f = floorf(xs);
        float wy = __fsub_rn(ys, y0f);
        float wx = __fsub_rn(xs, x0f);
        int y0i = (int)fminf(fmaxf(y0f, 0.0f), 511.0f);
        int y1i = (int)fminf(fmaxf(__fadd_rn(y0f, 1.0f), 0.0f), 511.0f);
        int x0i = (int)fminf(fmaxf(x0f, 0.0f), 511.0f);
        int x1i = (int)fminf(fmaxf(__fadd_rn(x0f, 1.0f), 0.0f), 511.0f);
        float v00 = (float)GM[((size_t)y0i * WW + x0i) * NGT];
        float v01 = (float)GM[((size_t)y0i * WW + x1i) * NGT];
        float v10 = (float)GM[((size_t)y1i * WW + x0i) * NGT];
        float v11 = (float)GM[((size_t)y1i * WW + x1i) * NGT];
        float omwx = __fsub_rn(1.0f, wx), omwy = __fsub_rn(1.0f, wy);
        float top = __fadd_rn(__fmul_rn(v00, omwx), __fmul_rn(v01, wx));
        float bot = __fadd_rn(__fmul_rn(v10, omwx), __fmul_rn(v11, wx));
        float val = __fadd_rn(__fmul_rn(top, omwy), __fmul_rn(bot, wy));
        bool ok = (ys >= 0.0f) && (ys <= 511.0f) && (xs >= 0.0f) && (xs <= 511.0f);
        val = ok ? val : 0.0f;
        mout[p] = rintf(val);   // jnp.round = half-to-even
    }
}

extern "C" void kernel_launch(void* const* d_in, const int* in_sizes, int n_in,
                              void* d_out, int out_size, void* d_ws, size_t ws_size,
                              hipStream_t stream) {
    const float* props = (const float*)d_in[0];   // (2,2000,4) f32
    const int*   gcls  = (const int*)  d_in[1];   // (2,100) i32
    const float* gbox  = (const float*)d_in[2];   // (2,100,4) f32
    const int*   gmask = (const int*)  d_in[3];   // (2,512,512,100) bool->i32
    float* out = (float*)d_out;
    int* wsi = (int*)d_ws;

    dim3 gA(16, 2);
    k_flags<<<gA, 256, 0, stream>>>(props, gcls, gbox, wsi);
    k_rows<<<2 * TR, 256, 0, stream>>>(props, gcls, gbox, gmask, wsi, out);
}